// Round 10
// baseline (1924.036 us; speedup 1.0000x reference)
//
#include <hip/hip_runtime.h>
#include <hip/hip_cooperative_groups.h>
#include <cstdint>

namespace cg = cooperative_groups;

#define NN 10000
#define NE 80000
#define DIN_ 1024
#define HH 512

typedef __attribute__((ext_vector_type(8))) short bf16x8;
typedef __attribute__((ext_vector_type(4))) float f32x4;
typedef unsigned short u16;
typedef unsigned int u32;

static __device__ __forceinline__ float b2f(u16 u) {
  u32 i = ((u32)u) << 16;
  return __builtin_bit_cast(float, i);
}
static __device__ __forceinline__ u16 f2b(float f) {
  u32 i = __builtin_bit_cast(u32, f);
  u32 r = (i + 0x7fffu + ((i >> 16) & 1u)) >> 16;
  return (u16)r;
}
static __device__ __forceinline__ void unpack8(uint4 u, float* f) {
  f[0] = __builtin_bit_cast(float, u.x << 16);
  f[1] = __builtin_bit_cast(float, u.x & 0xffff0000u);
  f[2] = __builtin_bit_cast(float, u.y << 16);
  f[3] = __builtin_bit_cast(float, u.y & 0xffff0000u);
  f[4] = __builtin_bit_cast(float, u.z << 16);
  f[5] = __builtin_bit_cast(float, u.z & 0xffff0000u);
  f[6] = __builtin_bit_cast(float, u.w << 16);
  f[7] = __builtin_bit_cast(float, u.w & 0xffff0000u);
}
static __device__ __forceinline__ void load8(const u16* p, float* f) { unpack8(*(const uint4*)p, f); }

#define ASYNC_CP16(gp, lp)                                                        \
  __builtin_amdgcn_global_load_lds((__attribute__((address_space(1))) void*)(gp), \
                                   (__attribute__((address_space(3))) void*)(lp), \
                                   16, 0, 0)

// per-block dtype flags
static __device__ __forceinline__ int float_flag(const u16* xw) {
  __shared__ int c;
  if (threadIdx.x == 0) c = 0;
  __syncthreads();
  int bad = 0;
  for (int i = threadIdx.x; i < 2048; i += blockDim.x) {
    u32 e = (xw[i] >> 7) & 0xFFu;
    if (e >= 140u) bad++;  // |v|>=2^13 impossible for bf16 x~N(0,1)
  }
  if (bad) atomicAdd(&c, bad);
  __syncthreads();
  return c > 64;
}
static __device__ __forceinline__ int int64_flag(const u32* ew) {
  __shared__ int c;
  if (threadIdx.x == 0) c = 0;
  __syncthreads();
  int z = 0;
  for (int i = threadIdx.x; i < 256; i += blockDim.x)
    if (ew[2 * i + 1] == 0u) z++;
  if (z) atomicAdd(&c, z);
  __syncthreads();
  return c > 200;
}

// ---------------- edges: dtype cvt + degree count ----------------
__global__ void k_edges(const void* ei, int* esrc, int* edst, int* counts) {
  int f64 = int64_flag((const u32*)ei);
  int i = blockIdx.x * 256 + threadIdx.x;
  if (i < NE) {
    int sv, dv;
    if (f64) {
      sv = (int)((const long long*)ei)[i];
      dv = (int)((const long long*)ei)[NE + i];
    } else {
      sv = ((const int*)ei)[i];
      dv = ((const int*)ei)[NE + i];
    }
    esrc[i] = sv;
    edst[i] = dv;
    atomicAdd(&counts[dv], 1);
  } else if (i < NE + NN) {
    atomicAdd(&counts[i - NE], 1);  // self-loop
  }
}

// ---------------- fused: single-block scan (block 0) + xc conversion (other blocks) ----------------
#define CONVB 2047
__global__ __launch_bounds__(512) void k_scanconv(const int* counts, int* rowptr, int* cursor, int n,
                                                  const void* xin, u16* xout) {
  if (blockIdx.x == 0) {
    __shared__ int lds[512];
    const int PER = 20;
    int t = threadIdx.x;
    int base = t * PER;
    int v[PER];
    int sum = 0;
#pragma unroll
    for (int i = 0; i < PER; i++) {
      int idx = base + i;
      v[i] = (idx < n) ? counts[idx] : 0;
      sum += v[i];
    }
    lds[t] = sum;
    __syncthreads();
    for (int off = 1; off < 512; off <<= 1) {
      int x = (t >= off) ? lds[t - off] : 0;
      __syncthreads();
      lds[t] += x;
      __syncthreads();
    }
    int run = (t > 0) ? lds[t - 1] : 0;
#pragma unroll
    for (int i = 0; i < PER; i++) {
      int idx = base + i;
      if (idx < n) {
        cursor[idx] = run;
        run += v[i];
        rowptr[idx + 1] = run;
      }
    }
    if (t == 0) rowptr[0] = 0;
    return;
  }
  int f = float_flag((const u16*)xin);
  const int total = NN * DIN_ / 8;
  for (int g = (blockIdx.x - 1) * 512 + threadIdx.x; g < total; g += CONVB * 512) {
    u16 o[8];
    if (f) {
      const float* p = (const float*)xin + (size_t)g * 8;
#pragma unroll
      for (int i = 0; i < 8; i++) o[i] = f2b(p[i]);
    } else {
      *(uint4*)o = *((const uint4*)xin + g);
    }
    *((uint4*)xout + g) = *(const uint4*)o;
  }
}

// ---------------- fused: scatter + 20 vectors + 10 weight transposes ----------------
#define SBLK 352   // scatter blocks: ceil((NE+NN)/256)
struct Prep {
  const int* esrc;
  const int* edst;
  int* cursor;
  int* col;
  const void* xin;
  const void* vin[20];
  u16* vout[20];
  int vn[20];
  const void* tin[10];
  u16* tout[10];
  int tK[10], tN[10], toff[10];
};
__global__ void k_prep(Prep a) {
  __shared__ u16 tt[32][33];
  int b = blockIdx.x;
  if (b < SBLK) {
    int i = b * 256 + threadIdx.x;
    if (i < NE) {
      int p = atomicAdd(&a.cursor[a.edst[i]], 1);
      a.col[p] = a.esrc[i];
    } else if (i < NE + NN) {
      int v = i - NE;
      int p = atomicAdd(&a.cursor[v], 1);
      a.col[p] = v;  // self-loop
    }
    return;
  }
  b -= SBLK;
  int f = float_flag((const u16*)a.xin);
  if (b < 20) {
    int v = b;
    const void* in = a.vin[v];
    u16* out = a.vout[v];
    int n = a.vn[v];
    for (int i = threadIdx.x; i < n; i += 256)
      out[i] = f ? f2b(((const float*)in)[i]) : ((const u16*)in)[i];
  } else {
    int tb = b - 20;
    int seg = 0;
#pragma unroll
    for (int i = 1; i < 10; i++)
      if (tb >= a.toff[i]) seg = i;
    int tl = tb - a.toff[seg];
    int K = a.tK[seg], N = a.tN[seg];
    int tiles_n = N >> 5;
    int n0 = (tl % tiles_n) << 5, k0 = (tl / tiles_n) << 5;
    const void* in = a.tin[seg];
    u16* out = a.tout[seg];
    int tx = threadIdx.x & 31, ty = threadIdx.x >> 5;
    for (int r = ty; r < 32; r += 8) {
      size_t idx = (size_t)(k0 + r) * N + n0 + tx;
      tt[r][tx] = f ? f2b(((const float*)in)[idx]) : ((const u16*)in)[idx];
    }
    __syncthreads();
    for (int r = ty; r < 32; r += 8) out[(size_t)(n0 + r) * K + k0 + tx] = tt[tx][r];
  }
}

// ---------------- device phase: 64x128 MFMA GEMM tile (R3 known-good body) ----------------
static __device__ __forceinline__ void gemm_phase(u16* sA, u16* sB,
    const u16* __restrict__ A, int lda, const u16* __restrict__ Bt,
    const u16* __restrict__ bias, u16* __restrict__ C,
    int M, int N, int K, int act) {
  int tiles_m = (M + 63) >> 6;
  int tiles_n = N >> 7;
  int nt = tiles_m * tiles_n;
  int t = threadIdx.x;
  int wave = t >> 6, lane = t & 63;
  int srow = t >> 2;
  int sk = ((t & 3) ^ ((t >> 3) & 3)) * 8;  // XOR-swizzled k-chunk
  int wn = wave << 5;
  int lr = lane & 15;
  int kcs = (((lane >> 4) ^ ((lr >> 1) & 3))) * 8;
  int rbase = (lane >> 4) << 2;

  for (int tid = blockIdx.x; tid < nt; tid += gridDim.x) {
    int yt = tid / tiles_n;
    int xt = tid - yt * tiles_n;
    int m0 = yt << 6, n0 = xt << 7;

    const u16* agp[2];
    u16* la[2];
#pragma unroll
    for (int h = 0; h < 2; h++) {
      int ra = m0 + srow;
      ra = ra < M ? ra : M - 1;
      agp[h] = A + (size_t)ra * lda + h * 32 + sk;
      la[h] = sA + h * 2048 + t * 8;
    }
    const u16* bgp[4];
    u16* lb[4];
#pragma unroll
    for (int q = 0; q < 4; q++) {
      int h = q >> 1;
      int row = ((q & 1) << 6) + srow;
      bgp[q] = Bt + (size_t)(n0 + row) * K + h * 32 + sk;
      lb[q] = sB + h * 4096 + (((q & 1) << 8) + t) * 8;
    }

    f32x4 acc[4][2];
#pragma unroll
    for (int i = 0; i < 4; i++)
#pragma unroll
      for (int j = 0; j < 2; j++) acc[i][j] = (f32x4){0.f, 0.f, 0.f, 0.f};

    for (int k0 = 0; k0 < K; k0 += 64) {
#pragma unroll
      for (int h = 0; h < 2; h++) ASYNC_CP16(agp[h] + k0, la[h]);
#pragma unroll
      for (int q = 0; q < 4; q++) ASYNC_CP16(bgp[q] + k0, lb[q]);
      __syncthreads();
      bf16x8 a[2][4], b[2][2];
#pragma unroll
      for (int s = 0; s < 2; s++) {
#pragma unroll
        for (int i = 0; i < 4; i++) a[s][i] = *(const bf16x8*)(sA + s * 2048 + (i * 16 + lr) * 32 + kcs);
#pragma unroll
        for (int j = 0; j < 2; j++) b[s][j] = *(const bf16x8*)(sB + s * 4096 + (wn + j * 16 + lr) * 32 + kcs);
      }
#pragma unroll
      for (int s = 0; s < 2; s++)
#pragma unroll
        for (int i = 0; i < 4; i++)
#pragma unroll
          for (int j = 0; j < 2; j++)
            acc[i][j] = __builtin_amdgcn_mfma_f32_16x16x32_bf16(a[s][i], b[s][j], acc[i][j], 0, 0, 0);
      __syncthreads();  // also protects LDS reuse by the next tile iteration
    }

#pragma unroll
    for (int j = 0; j < 2; j++) {
      int colc = n0 + wn + j * 16 + lr;
      float bv = b2f(bias[colc]);
#pragma unroll
      for (int i = 0; i < 4; i++) {
#pragma unroll
        for (int r = 0; r < 4; r++) {
          int row = m0 + i * 16 + rbase + r;
          if (row < M) {
            float v = acc[i][j][r] + bv;
            if (act) v = fmaxf(v, 0.f);
            C[(size_t)row * N + colc] = f2b(v);
          }
        }
      }
    }
  }
}

// ---------------- device phase: single-pass GATv2 attention (attn5 body, wave-stride) ----------------
static __device__ __forceinline__ void attn_phase(u16* __restrict__ xlr,
    const u16* __restrict__ att, const u16* __restrict__ bias,
    const int* __restrict__ rowptr, const int* __restrict__ col, int n) {
  int lane = threadIdx.x & 63;
  int h0 = lane * 8;
  int slot = blockIdx.x * 4 + (threadIdx.x >> 6);
  int nslots = gridDim.x * 4;
  float a[8];
  load8(att + h0, a);
  float bv[8];
  load8(bias + h0, bv);

  for (int node = slot; node < n; node += nslots) {
    float r[8];
    load8(xlr + (size_t)node * 1024 + 512 + h0, r);
    int e0 = rowptr[node], e1 = rowptr[node + 1];

    float m = -3e38f, s = 0.f;
    float acc[8] = {0.f, 0.f, 0.f, 0.f, 0.f, 0.f, 0.f, 0.f};
    int j0 = col[e0];
    int j1 = col[(e0 + 1 < e1) ? e0 + 1 : e0];
    uint4 raw0 = *(const uint4*)(xlr + (size_t)j0 * 1024 + h0);
    uint4 raw1 = *(const uint4*)(xlr + (size_t)j1 * 1024 + h0);

    for (int e = e0; e < e1; e += 2) {
      bool has2 = (e + 1 < e1);
      int jn0 = col[(e + 2 < e1) ? e + 2 : e1 - 1];
      int jn1 = col[(e + 3 < e1) ? e + 3 : e1 - 1];
      uint4 p0 = *(const uint4*)(xlr + (size_t)jn0 * 1024 + h0);  // prefetch next pair
      uint4 p1 = *(const uint4*)(xlr + (size_t)jn1 * 1024 + h0);
      float x0[8], x1[8];
      unpack8(raw0, x0);
      unpack8(raw1, x1);
      float pa = 0.f, pb = 0.f;
#pragma unroll
      for (int i = 0; i < 8; i++) {
        float z0 = x0[i] + r[i];
        z0 = z0 > 0.f ? z0 : 0.2f * z0;
        pa = fmaf(a[i], z0, pa);
        float z1 = x1[i] + r[i];
        z1 = z1 > 0.f ? z1 : 0.2f * z1;
        pb = fmaf(a[i], z1, pb);
      }
#pragma unroll
      for (int off = 32; off >= 1; off >>= 1) {
        pa += __shfl_xor(pa, off);
        pb += __shfl_xor(pb, off);
      }
      if (pa > m) {
        float al = __expf(m - pa);  // first edge: exp(-inf)=0
        s = fmaf(s, al, 1.f);
#pragma unroll
        for (int i = 0; i < 8; i++) acc[i] = fmaf(acc[i], al, x0[i]);
        m = pa;
      } else {
        float w = __expf(pa - m);
        s += w;
#pragma unroll
        for (int i = 0; i < 8; i++) acc[i] = fmaf(w, x0[i], acc[i]);
      }
      if (has2) {
        if (pb > m) {
          float al = __expf(m - pb);
          s = fmaf(s, al, 1.f);
#pragma unroll
          for (int i = 0; i < 8; i++) acc[i] = fmaf(acc[i], al, x1[i]);
          m = pb;
        } else {
          float w = __expf(pb - m);
          s += w;
#pragma unroll
          for (int i = 0; i < 8; i++) acc[i] = fmaf(w, x1[i], acc[i]);
        }
      }
      raw0 = p0;
      raw1 = p1;
    }
    float inv = 1.f / (s + 1e-16f);
    uint4 o;
    u32 p8[8];
#pragma unroll
    for (int i = 0; i < 8; i++) {
      float v = fmaf(acc[i], inv, bv[i]);
      v = fmaxf(v, 0.f);
      p8[i] = f2b(v);
    }
    o.x = p8[0] | (p8[1] << 16);
    o.y = p8[2] | (p8[3] << 16);
    o.z = p8[4] | (p8[5] << 16);
    o.w = p8[6] | (p8[7] << 16);
    *(uint4*)(xlr + (size_t)node * 1024 + 512 + h0) = o;  // in-place over xr half
  }
}

// ---------------- device phase: final linear (256->2) + softmax ----------------
static __device__ __forceinline__ void head_phase(const u16* __restrict__ h2,
    const u16* __restrict__ lw3, const u16* __restrict__ lb3,
    float* __restrict__ out, int n) {
  int lane = threadIdx.x & 63;
  int k0 = lane * 4;
  int slot = blockIdx.x * 4 + (threadIdx.x >> 6);
  int nslots = gridDim.x * 4;
  float wv[8];
  load8(lw3 + (size_t)k0 * 2, wv);
  float bl0 = b2f(lb3[0]), bl1 = b2f(lb3[1]);
  for (int row = slot; row < n; row += nslots) {
    uint2 hu = *(const uint2*)(h2 + (size_t)row * 256 + k0);
    float hx[4];
    hx[0] = __builtin_bit_cast(float, hu.x << 16);
    hx[1] = __builtin_bit_cast(float, hu.x & 0xffff0000u);
    hx[2] = __builtin_bit_cast(float, hu.y << 16);
    hx[3] = __builtin_bit_cast(float, hu.y & 0xffff0000u);
    float p0 = 0.f, p1 = 0.f;
#pragma unroll
    for (int i = 0; i < 4; i++) {
      p0 = fmaf(hx[i], wv[2 * i], p0);
      p1 = fmaf(hx[i], wv[2 * i + 1], p1);
    }
#pragma unroll
    for (int off = 32; off >= 1; off >>= 1) {
      p0 += __shfl_xor(p0, off);
      p1 += __shfl_xor(p1, off);
    }
    if (lane == 0) {
      float l0 = p0 + bl0;
      float l1 = p1 + bl1;
      float mx = fmaxf(l0, l1);
      float q0 = __expf(l0 - mx), q1 = __expf(l1 - mx);
      float si = 1.f / (q0 + q1);
      out[row * 2 + 0] = l0;
      out[row * 2 + 1] = l1;
      out[2 * n + row * 2 + 0] = q0 * si;
      out[2 * n + row * 2 + 1] = q1 * si;
    }
  }
}

// ---------------- the fused cooperative kernel: 4x(GEMM->attn) + MLP + head ----------------
struct FusedArgs {
  const int* rowptr;
  const int* col;
  const u16* xc;
  u16 *X0, *X1, *mlp1, *mlp2;
  const u16 *comb0, *comb1, *comb2, *comb3;
  const u16 *cb, *attv, *bgv;
  const u16 *lw1T, *lb1v, *lw2T, *lb2v, *lw3v, *lb3v;
  float* out;
};

#define FENCE_SYNC() do { __threadfence(); g.sync(); __threadfence(); } while (0)

__global__ __launch_bounds__(256, 4) void k_fused(FusedArgs f) {
  __shared__ u16 sA[4096];
  __shared__ u16 sB[8192];
  cg::grid_group g = cg::this_grid();

  // Layer 1
  gemm_phase(sA, sB, f.xc, 1024, f.comb0, f.cb + 0 * 1024, f.X0, NN, 1024, 1024, 0);
  FENCE_SYNC();
  attn_phase(f.X0, f.attv + 0 * 512, f.bgv + 0 * 512, f.rowptr, f.col, NN);
  FENCE_SYNC();
  // Layer 2
  gemm_phase(sA, sB, f.X0 + 512, 1024, f.comb1, f.cb + 1 * 1024, f.X1, NN, 1024, 512, 0);
  FENCE_SYNC();
  attn_phase(f.X1, f.attv + 1 * 512, f.bgv + 1 * 512, f.rowptr, f.col, NN);
  FENCE_SYNC();
  // Layer 3
  gemm_phase(sA, sB, f.X1 + 512, 1024, f.comb2, f.cb + 2 * 1024, f.X0, NN, 1024, 512, 0);
  FENCE_SYNC();
  attn_phase(f.X0, f.attv + 2 * 512, f.bgv + 2 * 512, f.rowptr, f.col, NN);
  FENCE_SYNC();
  // Layer 4
  gemm_phase(sA, sB, f.X0 + 512, 1024, f.comb3, f.cb + 3 * 1024, f.X1, NN, 1024, 512, 0);
  FENCE_SYNC();
  attn_phase(f.X1, f.attv + 3 * 512, f.bgv + 3 * 512, f.rowptr, f.col, NN);
  FENCE_SYNC();
  // MLP head
  gemm_phase(sA, sB, f.X1 + 512, 1024, f.lw1T, f.lb1v, f.mlp1, NN, 512, 512, 1);
  FENCE_SYNC();
  gemm_phase(sA, sB, f.mlp1, 512, f.lw2T, f.lb2v, f.mlp2, NN, 256, 512, 1);
  FENCE_SYNC();
  head_phase(f.mlp2, f.lw3v, f.lb3v, f.out, NN);
}

extern "C" void kernel_launch(void* const* d_in, const int* in_sizes, int n_in,
                              void* d_out, int out_size, void* d_ws, size_t ws_size,
                              hipStream_t stream) {
  (void)in_sizes; (void)n_in; (void)out_size; (void)ws_size;
  const void* x_raw = d_in[0];
  const void* ei_raw = d_in[1];
  const void *wl[4], *bl[4], *wr[4], *br[4], *att[4], *bg[4];
  for (int i = 0; i < 4; i++) {
    wl[i] = d_in[2 + i * 6 + 0];
    bl[i] = d_in[2 + i * 6 + 1];
    wr[i] = d_in[2 + i * 6 + 2];
    br[i] = d_in[2 + i * 6 + 3];
    att[i] = d_in[2 + i * 6 + 4];
    bg[i] = d_in[2 + i * 6 + 5];
  }
  const void* lw1 = d_in[26];
  const void* lb1 = d_in[27];
  const void* lw2 = d_in[28];
  const void* lb2 = d_in[29];
  const void* lw3 = d_in[30];
  const void* lb3 = d_in[31];

  size_t off = 0;
  auto alloc = [&](size_t bytes) -> void* {
    off = (off + 255) & ~(size_t)255;
    void* p = (char*)d_ws + off;
    off += bytes;
    return p;
  };
  int* esrc = (int*)alloc(NE * 4);
  int* edst = (int*)alloc(NE * 4);
  int* counts = (int*)alloc(NN * 4);
  int* rowptr = (int*)alloc((NN + 1) * 4);
  int* cursor = (int*)alloc(NN * 4);
  int* col = (int*)alloc((NE + NN) * 4);
  u16* cb = (u16*)alloc(4 * 1024 * 2);
  u16* attv = (u16*)alloc(4 * 512 * 2);
  u16* bgv = (u16*)alloc(4 * 512 * 2);
  u16* lb1v = (u16*)alloc(512 * 2);
  u16* lb2v = (u16*)alloc(256 * 2);
  u16* lw3v = (u16*)alloc(512 * 2);
  u16* lb3v = (u16*)alloc(2 * 2);
  u16* comb0 = (u16*)alloc((size_t)1024 * 1024 * 2);
  u16* combL[4];
  combL[0] = comb0;
  for (int l = 1; l < 4; l++) combL[l] = (u16*)alloc((size_t)1024 * 512 * 2);
  u16* lw1T = (u16*)alloc((size_t)512 * 512 * 2);
  u16* lw2T = (u16*)alloc((size_t)256 * 512 * 2);
  u16* xc = (u16*)alloc((size_t)NN * DIN_ * 2);
  u16* X0 = (u16*)alloc((size_t)NN * 1024 * 2);
  u16* X1 = (u16*)alloc((size_t)NN * 1024 * 2);
  u16* mlp1 = xc;                       // xc dead after layer-1 GEMM
  u16* mlp2 = xc + (size_t)NN * 512;

  // --- CSR stage 1 ---
  hipMemsetAsync(counts, 0, NN * 4, stream);
  int ET = NE + NN;
  k_edges<<<(ET + 255) / 256, 256, 0, stream>>>(ei_raw, esrc, edst, counts);
  // scan (block 0) + xc conversion (blocks 1..CONVB) in one launch
  k_scanconv<<<1 + CONVB, 512, 0, stream>>>(counts, rowptr, cursor, NN, x_raw, xc);

  // --- fused scatter + prep ---
  Prep pa;
  pa.esrc = esrc;
  pa.edst = edst;
  pa.cursor = cursor;
  pa.col = col;
  pa.xin = x_raw;
  for (int l = 0; l < 4; l++) {
    pa.vin[l * 4 + 0] = bl[l];  pa.vout[l * 4 + 0] = cb + l * 1024;        pa.vn[l * 4 + 0] = 512;
    pa.vin[l * 4 + 1] = br[l];  pa.vout[l * 4 + 1] = cb + l * 1024 + 512;  pa.vn[l * 4 + 1] = 512;
    pa.vin[l * 4 + 2] = att[l]; pa.vout[l * 4 + 2] = attv + l * 512;       pa.vn[l * 4 + 2] = 512;
    pa.vin[l * 4 + 3] = bg[l];  pa.vout[l * 4 + 3] = bgv + l * 512;        pa.vn[l * 4 + 3] = 512;
  }
  pa.vin[16] = lb1; pa.vout[16] = lb1v; pa.vn[16] = 512;
  pa.vin[17] = lb2; pa.vout[17] = lb2v; pa.vn[17] = 256;
  pa.vin[18] = lw3; pa.vout[18] = lw3v; pa.vn[18] = 512;
  pa.vin[19] = lb3; pa.vout[19] = lb3v; pa.vn[19] = 2;
  const void* tin[10] = {wl[0], wr[0], wl[1], wr[1], wl[2], wr[2], wl[3], wr[3], lw1, lw2};
  u16* tout[10] = {comb0, comb0 + (size_t)512 * 1024,
                   combL[1], combL[1] + (size_t)512 * 512,
                   combL[2], combL[2] + (size_t)512 * 512,
                   combL[3], combL[3] + (size_t)512 * 512,
                   lw1T, lw2T};
  int tK[10] = {1024, 1024, 512, 512, 512, 512, 512, 512, 512, 512};
  int tN[10] = {512, 512, 512, 512, 512, 512, 512, 512, 512, 256};
  int acc_off = 0;
  for (int i = 0; i < 10; i++) {
    pa.tin[i] = tin[i];
    pa.tout[i] = tout[i];
    pa.tK[i] = tK[i];
    pa.tN[i] = tN[i];
    pa.toff[i] = acc_off;
    acc_off += (tN[i] >> 5) * (tK[i] >> 5);
  }
  k_prep<<<SBLK + 20 + acc_off, 256, 0, stream>>>(pa);

  // --- one cooperative kernel for the whole dependent chain ---
  FusedArgs fa;
  fa.rowptr = rowptr;
  fa.col = col;
  fa.xc = xc;
  fa.X0 = X0;
  fa.X1 = X1;
  fa.mlp1 = mlp1;
  fa.mlp2 = mlp2;
  fa.comb0 = comb0;
  fa.comb1 = combL[1];
  fa.comb2 = combL[2];
  fa.comb3 = combL[3];
  fa.cb = cb;
  fa.attv = attv;
  fa.bgv = bgv;
  fa.lw1T = lw1T;
  fa.lb1v = lb1v;
  fa.lw2T = lw2T;
  fa.lb2v = lb2v;
  fa.lw3v = lw3v;
  fa.lb3v = lb3v;
  fa.out = (float*)d_out;

  int nb = 0;
  hipOccupancyMaxActiveBlocksPerMultiprocessor(&nb, k_fused, 256, 0);
  if (nb < 1) nb = 1;
  long long grid = (long long)nb * 256;  // 256 CUs on MI355X
  if (grid > 1256) grid = 1256;          // max useful (L1 tile count)
  void* kargs[] = {(void*)&fa};
  hipLaunchCooperativeKernel((void*)k_fused, dim3((u32)grid), dim3(256), kargs, 0, stream);
}

// Round 11
// 398.634 us; speedup vs baseline: 4.8266x; 4.8266x over previous
//
#include <hip/hip_runtime.h>
#include <cstdint>

#define NN 10000
#define NE 80000
#define DIN_ 1024
#define HH 512

typedef __attribute__((ext_vector_type(8))) short bf16x8;
typedef __attribute__((ext_vector_type(4))) float f32x4;
typedef unsigned short u16;
typedef unsigned int u32;

static __device__ __forceinline__ float b2f(u16 u) {
  u32 i = ((u32)u) << 16;
  return __builtin_bit_cast(float, i);
}
static __device__ __forceinline__ u16 f2b(float f) {
  u32 i = __builtin_bit_cast(u32, f);
  u32 r = (i + 0x7fffu + ((i >> 16) & 1u)) >> 16;
  return (u16)r;
}
static __device__ __forceinline__ void unpack8(uint4 u, float* f) {
  f[0] = __builtin_bit_cast(float, u.x << 16);
  f[1] = __builtin_bit_cast(float, u.x & 0xffff0000u);
  f[2] = __builtin_bit_cast(float, u.y << 16);
  f[3] = __builtin_bit_cast(float, u.y & 0xffff0000u);
  f[4] = __builtin_bit_cast(float, u.z << 16);
  f[5] = __builtin_bit_cast(float, u.z & 0xffff0000u);
  f[6] = __builtin_bit_cast(float, u.w << 16);
  f[7] = __builtin_bit_cast(float, u.w & 0xffff0000u);
}
static __device__ __forceinline__ void load8(const u16* p, float* f) { unpack8(*(const uint4*)p, f); }

#define ASYNC_CP16(gp, lp)                                                        \
  __builtin_amdgcn_global_load_lds((__attribute__((address_space(1))) void*)(gp), \
                                   (__attribute__((address_space(3))) void*)(lp), \
                                   16, 0, 0)

// per-block dtype flags
static __device__ __forceinline__ int float_flag(const u16* xw) {
  __shared__ int c;
  if (threadIdx.x == 0) c = 0;
  __syncthreads();
  int bad = 0;
  for (int i = threadIdx.x; i < 2048; i += blockDim.x) {
    u32 e = (xw[i] >> 7) & 0xFFu;
    if (e >= 140u) bad++;  // |v|>=2^13 impossible for bf16 x~N(0,1)
  }
  if (bad) atomicAdd(&c, bad);
  __syncthreads();
  return c > 64;
}
static __device__ __forceinline__ int int64_flag(const u32* ew) {
  __shared__ int c;
  if (threadIdx.x == 0) c = 0;
  __syncthreads();
  int z = 0;
  for (int i = threadIdx.x; i < 256; i += blockDim.x)
    if (ew[2 * i + 1] == 0u) z++;
  if (z) atomicAdd(&c, z);
  __syncthreads();
  return c > 200;
}

// ---------------- fused front-end: CSR build + dtype converts, ONE launch ----------------
// block 0: LDS histogram of dst (read raw edges directly) + scan -> rowptr/cursor
// blocks 1..EBLK: esrc/edst dtype convert
// blocks EBLK+1..: x conversion fp32->bf16 (or copy)
// Replaces memset + k_edges + k_scanconv (saves 2 kernel boundaries).
#define EBLK 157   // ceil(NE/512)
#define CONVB 2048
__global__ __launch_bounds__(512) void k_front(const void* ei, int* esrc, int* edst,
                                               int* rowptr, int* cursor,
                                               const void* xin, u16* xout) {
  __shared__ int hist[NN];   // 40 KB
  __shared__ int lds[512];
  int b = blockIdx.x;
  int t = threadIdx.x;
  if (b == 0) {
    for (int i = t; i < NN; i += 512) hist[i] = 0;
    int f64 = int64_flag((const u32*)ei);  // includes a __syncthreads after hist zeroing
    __syncthreads();
    if (f64) {
      const long long* dd = (const long long*)ei + NE;
      for (int i = t; i < NE; i += 512) atomicAdd(&hist[(int)dd[i]], 1);
    } else {
      const int* dd = (const int*)ei + NE;
      for (int i = t; i < NE; i += 512) atomicAdd(&hist[dd[i]], 1);
    }
    __syncthreads();
    const int PER = 20;
    int base = t * PER;
    int v[PER];
    int sum = 0;
#pragma unroll
    for (int i = 0; i < PER; i++) {
      int idx = base + i;
      v[i] = (idx < NN) ? hist[idx] + 1 : 0;  // +1 = self-loop
      sum += v[i];
    }
    lds[t] = sum;
    __syncthreads();
    for (int off = 1; off < 512; off <<= 1) {
      int x = (t >= off) ? lds[t - off] : 0;
      __syncthreads();
      lds[t] += x;
      __syncthreads();
    }
    int run = (t > 0) ? lds[t - 1] : 0;
#pragma unroll
    for (int i = 0; i < PER; i++) {
      int idx = base + i;
      if (idx < NN) {
        cursor[idx] = run;
        run += v[i];
        rowptr[idx + 1] = run;
      }
    }
    if (t == 0) rowptr[0] = 0;
    return;
  }
  if (b <= EBLK) {
    int f64 = int64_flag((const u32*)ei);
    int i = (b - 1) * 512 + t;
    if (i < NE) {
      if (f64) {
        esrc[i] = (int)((const long long*)ei)[i];
        edst[i] = (int)((const long long*)ei)[NE + i];
      } else {
        esrc[i] = ((const int*)ei)[i];
        edst[i] = ((const int*)ei)[NE + i];
      }
    }
    return;
  }
  // x conversion blocks
  int f = float_flag((const u16*)xin);
  const int total = NN * DIN_ / 8;
  for (int g = (b - 1 - EBLK) * 512 + t; g < total; g += CONVB * 512) {
    u16 o[8];
    if (f) {
      const float* p = (const float*)xin + (size_t)g * 8;
#pragma unroll
      for (int i = 0; i < 8; i++) o[i] = f2b(p[i]);
    } else {
      *(uint4*)o = *((const uint4*)xin + g);
    }
    *((uint4*)xout + g) = *(const uint4*)o;
  }
}

// ---------------- fused: scatter + 20 vectors + 10 weight transposes ----------------
#define SBLK 352   // scatter blocks: ceil((NE+NN)/256)
struct Prep {
  const int* esrc;
  const int* edst;
  int* cursor;
  int* col;
  const void* xin;
  const void* vin[20];
  u16* vout[20];
  int vn[20];
  const void* tin[10];
  u16* tout[10];
  int tK[10], tN[10], toff[10];
};
__global__ void k_prep(Prep a) {
  __shared__ u16 tt[32][33];
  int b = blockIdx.x;
  if (b < SBLK) {
    int i = b * 256 + threadIdx.x;
    if (i < NE) {
      int p = atomicAdd(&a.cursor[a.edst[i]], 1);
      a.col[p] = a.esrc[i];
    } else if (i < NE + NN) {
      int v = i - NE;
      int p = atomicAdd(&a.cursor[v], 1);
      a.col[p] = v;  // self-loop
    }
    return;
  }
  b -= SBLK;
  int f = float_flag((const u16*)a.xin);
  if (b < 20) {
    int v = b;
    const void* in = a.vin[v];
    u16* out = a.vout[v];
    int n = a.vn[v];
    for (int i = threadIdx.x; i < n; i += 256)
      out[i] = f ? f2b(((const float*)in)[i]) : ((const u16*)in)[i];
  } else {
    int tb = b - 20;
    int seg = 0;
#pragma unroll
    for (int i = 1; i < 10; i++)
      if (tb >= a.toff[i]) seg = i;
    int tl = tb - a.toff[seg];
    int K = a.tK[seg], N = a.tN[seg];
    int tiles_n = N >> 5;
    int n0 = (tl % tiles_n) << 5, k0 = (tl / tiles_n) << 5;
    const void* in = a.tin[seg];
    u16* out = a.tout[seg];
    int tx = threadIdx.x & 31, ty = threadIdx.x >> 5;
    for (int r = ty; r < 32; r += 8) {
      size_t idx = (size_t)(k0 + r) * N + n0 + tx;
      tt[r][tx] = f ? f2b(((const float*)in)[idx]) : ((const u16*)in)[idx];
    }
    __syncthreads();
    for (int r = ty; r < 32; r += 8) out[(size_t)(n0 + r) * K + k0 + tx] = tt[tx][r];
  }
}

// ---------------- 64x128 MFMA GEMM, BK=64 single-buffer (R3 known-good) ----------------
__global__ __launch_bounds__(256) void k_gemm64(const u16* __restrict__ A, int lda,
                                                const u16* __restrict__ Bt,
                                                const u16* __restrict__ bias,
                                                u16* __restrict__ C,
                                                int M, int N, int K, int act,
                                                int tiles_m, int ln_tiles_n) {
  __shared__ u16 sA[2 * 64 * 32];    // 8 KB: two 32-k halves, 64 rows
  __shared__ u16 sB[2 * 128 * 32];   // 16 KB
  int id = blockIdx.x;
  int xcd = id & 7;
  int rest = id >> 3;
  int xt = rest & ((1 << ln_tiles_n) - 1);
  int yt = ((rest >> ln_tiles_n) << 3) + xcd;
  if (yt >= tiles_m) return;
  int m0 = yt << 6, n0 = xt << 7;
  int t = threadIdx.x;
  int wave = t >> 6, lane = t & 63;

  int srow = t >> 2;                        // 0..63
  int sk = ((t & 3) ^ ((t >> 3) & 3)) * 8;  // XOR-swizzled k-chunk
  const u16* agp[2];
  u16* la[2];
#pragma unroll
  for (int h = 0; h < 2; h++) {
    int ra = m0 + srow;
    ra = ra < M ? ra : M - 1;
    agp[h] = A + (size_t)ra * lda + h * 32 + sk;
    la[h] = sA + h * 2048 + t * 8;
  }
  const u16* bgp[4];
  u16* lb[4];
#pragma unroll
  for (int q = 0; q < 4; q++) {
    int h = q >> 1;
    int row = ((q & 1) << 6) + srow;
    bgp[q] = Bt + (size_t)(n0 + row) * K + h * 32 + sk;
    lb[q] = sB + h * 4096 + (((q & 1) << 8) + t) * 8;
  }

  int wn = wave << 5;  // each wave owns a 64x32 output slab
  int lr = lane & 15;
  int kcs = (((lane >> 4) ^ ((lr >> 1) & 3))) * 8;

  f32x4 acc[4][2];
#pragma unroll
  for (int i = 0; i < 4; i++)
#pragma unroll
    for (int j = 0; j < 2; j++) acc[i][j] = (f32x4){0.f, 0.f, 0.f, 0.f};

  for (int k0 = 0; k0 < K; k0 += 64) {
#pragma unroll
    for (int h = 0; h < 2; h++) ASYNC_CP16(agp[h] + k0, la[h]);
#pragma unroll
    for (int q = 0; q < 4; q++) ASYNC_CP16(bgp[q] + k0, lb[q]);
    __syncthreads();
    bf16x8 a[2][4], b[2][2];
#pragma unroll
    for (int s = 0; s < 2; s++) {
#pragma unroll
      for (int i = 0; i < 4; i++) a[s][i] = *(const bf16x8*)(sA + s * 2048 + (i * 16 + lr) * 32 + kcs);
#pragma unroll
      for (int j = 0; j < 2; j++) b[s][j] = *(const bf16x8*)(sB + s * 4096 + (wn + j * 16 + lr) * 32 + kcs);
    }
#pragma unroll
    for (int s = 0; s < 2; s++)
#pragma unroll
      for (int i = 0; i < 4; i++)
#pragma unroll
        for (int j = 0; j < 2; j++)
          acc[i][j] = __builtin_amdgcn_mfma_f32_16x16x32_bf16(a[s][i], b[s][j], acc[i][j], 0, 0, 0);
    __syncthreads();
  }

  int rbase = (lane >> 4) << 2;
#pragma unroll
  for (int j = 0; j < 2; j++) {
    int colc = n0 + wn + j * 16 + lr;
    float bv = b2f(bias[colc]);
#pragma unroll
    for (int i = 0; i < 4; i++) {
#pragma unroll
      for (int r = 0; r < 4; r++) {
        int row = m0 + i * 16 + rbase + r;
        if (row < M) {
          float v = acc[i][j][r] + bv;
          if (act) v = fmaxf(v, 0.f);
          C[(size_t)row * N + colc] = f2b(v);
        }
      }
    }
  }
}

// ---------------- single-pass GATv2 attention, 2-edge ILP, 1 exp per edge ----------------
__global__ __launch_bounds__(256) void k_attn5(u16* __restrict__ xlr,
                                               const u16* __restrict__ att, const u16* __restrict__ bias,
                                               const int* __restrict__ rowptr, const int* __restrict__ col,
                                               int n) {
  int node = (blockIdx.x * 256 + threadIdx.x) >> 6;
  if (node >= n) return;
  int lane = threadIdx.x & 63;
  int h0 = lane * 8;
  float a[8], r[8];
  load8(att + h0, a);
  load8(xlr + (size_t)node * 1024 + 512 + h0, r);
  int e0 = rowptr[node], e1 = rowptr[node + 1];

  float m = -3e38f, s = 0.f;
  float acc[8] = {0.f, 0.f, 0.f, 0.f, 0.f, 0.f, 0.f, 0.f};
  int j0 = col[e0];
  int j1 = col[(e0 + 1 < e1) ? e0 + 1 : e0];
  uint4 raw0 = *(const uint4*)(xlr + (size_t)j0 * 1024 + h0);
  uint4 raw1 = *(const uint4*)(xlr + (size_t)j1 * 1024 + h0);

  for (int e = e0; e < e1; e += 2) {
    bool has2 = (e + 1 < e1);
    int jn0 = col[(e + 2 < e1) ? e + 2 : e1 - 1];
    int jn1 = col[(e + 3 < e1) ? e + 3 : e1 - 1];
    uint4 p0 = *(const uint4*)(xlr + (size_t)jn0 * 1024 + h0);  // prefetch next pair
    uint4 p1 = *(const uint4*)(xlr + (size_t)jn1 * 1024 + h0);
    float x0[8], x1[8];
    unpack8(raw0, x0);
    unpack8(raw1, x1);
    float pa = 0.f, pb = 0.f;
#pragma unroll
    for (int i = 0; i < 8; i++) {
      float z0 = x0[i] + r[i];
      z0 = z0 > 0.f ? z0 : 0.2f * z0;
      pa = fmaf(a[i], z0, pa);
      float z1 = x1[i] + r[i];
      z1 = z1 > 0.f ? z1 : 0.2f * z1;
      pb = fmaf(a[i], z1, pb);
    }
#pragma unroll
    for (int off = 32; off >= 1; off >>= 1) {
      pa += __shfl_xor(pa, off);
      pb += __shfl_xor(pb, off);
    }
    // edge A: exactly one exp on the critical path (new-max edge has weight 1)
    if (pa > m) {
      float al = __expf(m - pa);  // first edge: exp(-inf)=0
      s = fmaf(s, al, 1.f);
#pragma unroll
      for (int i = 0; i < 8; i++) acc[i] = fmaf(acc[i], al, x0[i]);
      m = pa;
    } else {
      float w = __expf(pa - m);
      s += w;
#pragma unroll
      for (int i = 0; i < 8; i++) acc[i] = fmaf(w, x0[i], acc[i]);
    }
    if (has2) {
      if (pb > m) {
        float al = __expf(m - pb);
        s = fmaf(s, al, 1.f);
#pragma unroll
        for (int i = 0; i < 8; i++) acc[i] = fmaf(acc[i], al, x1[i]);
        m = pb;
      } else {
        float w = __expf(pb - m);
        s += w;
#pragma unroll
        for (int i = 0; i < 8; i++) acc[i] = fmaf(w, x1[i], acc[i]);
      }
    }
    raw0 = p0;
    raw1 = p1;
  }
  float inv = 1.f / (s + 1e-16f);

  float bv[8];
  load8(bias + h0, bv);
  uint4 o;
  u32 p8[8];
#pragma unroll
  for (int i = 0; i < 8; i++) {
    float v = fmaf(acc[i], inv, bv[i]);
    v = fmaxf(v, 0.f);
    p8[i] = f2b(v);
  }
  o.x = p8[0] | (p8[1] << 16);
  o.y = p8[2] | (p8[3] << 16);
  o.z = p8[4] | (p8[5] << 16);
  o.w = p8[6] | (p8[7] << 16);
  *(uint4*)(xlr + (size_t)node * 1024 + 512 + h0) = o;  // in-place over xr half
}

// ---------------- final linear (256->2) + softmax; fp32 out ----------------
__global__ __launch_bounds__(256) void k_head(const u16* __restrict__ h2, const u16* __restrict__ lw3,
                                              const u16* __restrict__ lb3, float* __restrict__ out, int n) {
  int row = (blockIdx.x * 256 + threadIdx.x) >> 6;
  if (row >= n) return;
  int lane = threadIdx.x & 63;
  int k0 = lane * 4;
  uint2 hu = *(const uint2*)(h2 + (size_t)row * 256 + k0);
  float hx[4];
  hx[0] = __builtin_bit_cast(float, hu.x << 16);
  hx[1] = __builtin_bit_cast(float, hu.x & 0xffff0000u);
  hx[2] = __builtin_bit_cast(float, hu.y << 16);
  hx[3] = __builtin_bit_cast(float, hu.y & 0xffff0000u);
  float wv[8];
  load8(lw3 + (size_t)k0 * 2, wv);
  float p0 = 0.f, p1 = 0.f;
#pragma unroll
  for (int i = 0; i < 4; i++) {
    p0 = fmaf(hx[i], wv[2 * i], p0);
    p1 = fmaf(hx[i], wv[2 * i + 1], p1);
  }
#pragma unroll
  for (int off = 32; off >= 1; off >>= 1) {
    p0 += __shfl_xor(p0, off);
    p1 += __shfl_xor(p1, off);
  }
  if (lane == 0) {
    float l0 = p0 + b2f(lb3[0]);
    float l1 = p1 + b2f(lb3[1]);
    float mx = fmaxf(l0, l1);
    float q0 = __expf(l0 - mx), q1 = __expf(l1 - mx);
    float si = 1.f / (q0 + q1);
    out[row * 2 + 0] = l0;
    out[row * 2 + 1] = l1;
    out[2 * n + row * 2 + 0] = q0 * si;
    out[2 * n + row * 2 + 1] = q1 * si;
  }
}

extern "C" void kernel_launch(void* const* d_in, const int* in_sizes, int n_in,
                              void* d_out, int out_size, void* d_ws, size_t ws_size,
                              hipStream_t stream) {
  (void)in_sizes; (void)n_in; (void)out_size; (void)ws_size;
  const void* x_raw = d_in[0];
  const void* ei_raw = d_in[1];
  const void *wl[4], *bl[4], *wr[4], *br[4], *att[4], *bg[4];
  for (int i = 0; i < 4; i++) {
    wl[i] = d_in[2 + i * 6 + 0];
    bl[i] = d_in[2 + i * 6 + 1];
    wr[i] = d_in[2 + i * 6 + 2];
    br[i] = d_in[2 + i * 6 + 3];
    att[i] = d_in[2 + i * 6 + 4];
    bg[i] = d_in[2 + i * 6 + 5];
  }
  const void* lw1 = d_in[26];
  const void* lb1 = d_in[27];
  const void* lw2 = d_in[28];
  const void* lb2 = d_in[29];
  const void* lw3 = d_in[30];
  const void* lb3 = d_in[31];

  size_t off = 0;
  auto alloc = [&](size_t bytes) -> void* {
    off = (off + 255) & ~(size_t)255;
    void* p = (char*)d_ws + off;
    off += bytes;
    return p;
  };
  int* esrc = (int*)alloc(NE * 4);
  int* edst = (int*)alloc(NE * 4);
  int* rowptr = (int*)alloc((NN + 1) * 4);
  int* cursor = (int*)alloc(NN * 4);
  int* col = (int*)alloc((NE + NN) * 4);
  u16* cb = (u16*)alloc(4 * 1024 * 2);
  u16* attv = (u16*)alloc(4 * 512 * 2);
  u16* bgv = (u16*)alloc(4 * 512 * 2);
  u16* lb1v = (u16*)alloc(512 * 2);
  u16* lb2v = (u16*)alloc(256 * 2);
  u16* lw3v = (u16*)alloc(512 * 2);
  u16* lb3v = (u16*)alloc(2 * 2);
  u16* comb0 = (u16*)alloc((size_t)1024 * 1024 * 2);
  u16* combL[4];
  combL[0] = comb0;
  for (int l = 1; l < 4; l++) combL[l] = (u16*)alloc((size_t)1024 * 512 * 2);
  u16* lw1T = (u16*)alloc((size_t)512 * 512 * 2);
  u16* lw2T = (u16*)alloc((size_t)256 * 512 * 2);
  u16* xc = (u16*)alloc((size_t)NN * DIN_ * 2);
  u16* X0 = (u16*)alloc((size_t)NN * 1024 * 2);
  u16* X1 = (u16*)alloc((size_t)NN * 1024 * 2);
  u16* mlp1 = xc;                       // xc dead after layer-1 GEMM
  u16* mlp2 = xc + (size_t)NN * 512;

  // --- fused front-end: histogram+scan (block 0) + edge cvt + x cvt, one launch ---
  k_front<<<1 + EBLK + CONVB, 512, 0, stream>>>(ei_raw, esrc, edst, rowptr, cursor, x_raw, xc);

  // --- fused scatter + prep ---
  Prep pa;
  pa.esrc = esrc;
  pa.edst = edst;
  pa.cursor = cursor;
  pa.col = col;
  pa.xin = x_raw;
  for (int l = 0; l < 4; l++) {
    pa.vin[l * 4 + 0] = bl[l];  pa.vout[l * 4 + 0] = cb + l * 1024;        pa.vn[l * 4 + 0] = 512;
    pa.vin[l * 4 + 1] = br[l];  pa.vout[l * 4 + 1] = cb + l * 1024 + 512;  pa.vn[l * 4 + 1] = 512;
    pa.vin[l * 4 + 2] = att[l]; pa.vout[l * 4 + 2] = attv + l * 512;       pa.vn[l * 4 + 2] = 512;
    pa.vin[l * 4 + 3] = bg[l];  pa.vout[l * 4 + 3] = bgv + l * 512;        pa.vn[l * 4 + 3] = 512;
  }
  pa.vin[16] = lb1; pa.vout[16] = lb1v; pa.vn[16] = 512;
  pa.vin[17] = lb2; pa.vout[17] = lb2v; pa.vn[17] = 256;
  pa.vin[18] = lw3; pa.vout[18] = lw3v; pa.vn[18] = 512;
  pa.vin[19] = lb3; pa.vout[19] = lb3v; pa.vn[19] = 2;
  const void* tin[10] = {wl[0], wr[0], wl[1], wr[1], wl[2], wr[2], wl[3], wr[3], lw1, lw2};
  u16* tout[10] = {comb0, comb0 + (size_t)512 * 1024,
                   combL[1], combL[1] + (size_t)512 * 512,
                   combL[2], combL[2] + (size_t)512 * 512,
                   combL[3], combL[3] + (size_t)512 * 512,
                   lw1T, lw2T};
  int tK[10] = {1024, 1024, 512, 512, 512, 512, 512, 512, 512, 512};
  int tN[10] = {512, 512, 512, 512, 512, 512, 512, 512, 512, 256};
  int acc_off = 0;
  for (int i = 0; i < 10; i++) {
    pa.tin[i] = tin[i];
    pa.tout[i] = tout[i];
    pa.tK[i] = tK[i];
    pa.tN[i] = tN[i];
    pa.toff[i] = acc_off;
    acc_off += (tN[i] >> 5) * (tK[i] >> 5);
  }
  k_prep<<<SBLK + 20 + acc_off, 256, 0, stream>>>(pa);

  auto gemm = [&](const u16* A, int lda, const u16* Bt, const u16* bias, u16* C,
                  int M, int Nn, int K, int act) {
    int tiles_m = (M + 63) >> 6;
    int tiles_n = Nn >> 7;
    int ln = (tiles_n == 8) ? 3 : (tiles_n == 4) ? 2 : 1;
    int mgrp = (tiles_m + 7) >> 3;
    int blocks = (mgrp << 3) * tiles_n;
    k_gemm64<<<blocks, 256, 0, stream>>>(A, lda, Bt, bias, C, M, Nn, K, act, tiles_m, ln);
  };
  auto attn = [&](u16* xlr, int l) {
    k_attn5<<<(NN * 64 + 255) / 256, 256, 0, stream>>>(xlr, attv + l * 512, bgv + l * 512,
                                                       rowptr, col, NN);
  };

  // Layer 1
  gemm(xc, 1024, comb0, cb + 0 * 1024, X0, NN, 1024, 1024, 0);
  attn(X0, 0);
  // Layer 2
  gemm(X0 + 512, 1024, combL[1], cb + 1 * 1024, X1, NN, 1024, 512, 0);
  attn(X1, 1);
  // Layer 3
  gemm(X1 + 512, 1024, combL[2], cb + 2 * 1024, X0, NN, 1024, 512, 0);
  attn(X0, 2);
  // Layer 4
  gemm(X0 + 512, 1024, combL[3], cb + 3 * 1024, X1, NN, 1024, 512, 0);
  attn(X1, 3);

  // MLP head (split: known-good occupancy)
  gemm(X1 + 512, 1024, lw1T, lb1v, mlp1, NN, 512, 512, 1);
  gemm(mlp1, 512, lw2T, lb2v, mlp2, NN, 256, 512, 1);
  k_head<<<(NN * 64 + 255) / 256, 256, 0, stream>>>(mlp2, lw3v, lb3v, (float*)d_out, NN);
}

// Round 12
// 360.854 us; speedup vs baseline: 5.3319x; 1.1047x over previous
//
#include <hip/hip_runtime.h>
#include <cstdint>

#define NN 10000
#define NE 80000
#define DIN_ 1024
#define HH 512

typedef __attribute__((ext_vector_type(8))) short bf16x8;
typedef __attribute__((ext_vector_type(4))) float f32x4;
typedef unsigned short u16;
typedef unsigned int u32;

static __device__ __forceinline__ float b2f(u16 u) {
  u32 i = ((u32)u) << 16;
  return __builtin_bit_cast(float, i);
}
static __device__ __forceinline__ u16 f2b(float f) {
  u32 i = __builtin_bit_cast(u32, f);
  u32 r = (i + 0x7fffu + ((i >> 16) & 1u)) >> 16;
  return (u16)r;
}
static __device__ __forceinline__ void unpack8(uint4 u, float* f) {
  f[0] = __builtin_bit_cast(float, u.x << 16);
  f[1] = __builtin_bit_cast(float, u.x & 0xffff0000u);
  f[2] = __builtin_bit_cast(float, u.y << 16);
  f[3] = __builtin_bit_cast(float, u.y & 0xffff0000u);
  f[4] = __builtin_bit_cast(float, u.z << 16);
  f[5] = __builtin_bit_cast(float, u.z & 0xffff0000u);
  f[6] = __builtin_bit_cast(float, u.w << 16);
  f[7] = __builtin_bit_cast(float, u.w & 0xffff0000u);
}
static __device__ __forceinline__ void load8(const u16* p, float* f) { unpack8(*(const uint4*)p, f); }

#define ASYNC_CP16(gp, lp)                                                        \
  __builtin_amdgcn_global_load_lds((__attribute__((address_space(1))) void*)(gp), \
                                   (__attribute__((address_space(3))) void*)(lp), \
                                   16, 0, 0)

// per-block dtype flags
static __device__ __forceinline__ int float_flag(const u16* xw) {
  __shared__ int c;
  if (threadIdx.x == 0) c = 0;
  __syncthreads();
  int bad = 0;
  for (int i = threadIdx.x; i < 2048; i += blockDim.x) {
    u32 e = (xw[i] >> 7) & 0xFFu;
    if (e >= 140u) bad++;  // |v|>=2^13 impossible for bf16 x~N(0,1)
  }
  if (bad) atomicAdd(&c, bad);
  __syncthreads();
  return c > 64;
}
static __device__ __forceinline__ int int64_flag(const u32* ew) {
  __shared__ int c;
  if (threadIdx.x == 0) c = 0;
  __syncthreads();
  int z = 0;
  for (int i = threadIdx.x; i < 256; i += blockDim.x)
    if (ew[2 * i + 1] == 0u) z++;
  if (z) atomicAdd(&c, z);
  __syncthreads();
  return c > 200;
}

// ---------------- L1: edges (cvt + degree count) + vec converts + weight transposes ----------------
// vec/transpose work depends only on raw inputs, so it rides the edges launch.
#define SBLK 352   // edge blocks: ceil((NE+NN)/256)
struct Prep {
  const void* ei;
  int* esrc;
  int* edst;
  int* counts;
  const void* xin;
  const void* vin[20];
  u16* vout[20];
  int vn[20];
  const void* tin[10];
  u16* tout[10];
  int tK[10], tN[10], toff[10];
};
__global__ void k_prep(Prep a) {
  __shared__ u16 tt[32][33];
  int b = blockIdx.x;
  if (b < SBLK) {  // edges: dtype cvt + degree count
    int f64 = int64_flag((const u32*)a.ei);
    int i = b * 256 + threadIdx.x;
    if (i < NE) {
      int sv, dv;
      if (f64) {
        sv = (int)((const long long*)a.ei)[i];
        dv = (int)((const long long*)a.ei)[NE + i];
      } else {
        sv = ((const int*)a.ei)[i];
        dv = ((const int*)a.ei)[NE + i];
      }
      a.esrc[i] = sv;
      a.edst[i] = dv;
      atomicAdd(&a.counts[dv], 1);
    } else if (i < NE + NN) {
      atomicAdd(&a.counts[i - NE], 1);  // self-loop
    }
    return;
  }
  b -= SBLK;
  int f = float_flag((const u16*)a.xin);
  if (b < 20) {
    int v = b;
    const void* in = a.vin[v];
    u16* out = a.vout[v];
    int n = a.vn[v];
    for (int i = threadIdx.x; i < n; i += 256)
      out[i] = f ? f2b(((const float*)in)[i]) : ((const u16*)in)[i];
  } else {
    int tb = b - 20;
    int seg = 0;
#pragma unroll
    for (int i = 1; i < 10; i++)
      if (tb >= a.toff[i]) seg = i;
    int tl = tb - a.toff[seg];
    int K = a.tK[seg], N = a.tN[seg];
    int tiles_n = N >> 5;
    int n0 = (tl % tiles_n) << 5, k0 = (tl / tiles_n) << 5;
    const void* in = a.tin[seg];
    u16* out = a.tout[seg];
    int tx = threadIdx.x & 31, ty = threadIdx.x >> 5;
    for (int r = ty; r < 32; r += 8) {
      size_t idx = (size_t)(k0 + r) * N + n0 + tx;
      tt[r][tx] = f ? f2b(((const float*)in)[idx]) : ((const u16*)in)[idx];
    }
    __syncthreads();
    for (int r = ty; r < 32; r += 8) out[(size_t)(n0 + r) * K + k0 + tx] = tt[tx][r];
  }
}

// ---------------- L2: single-block scan (block 0) + xc conversion (other blocks) ----------------
#define CONVB 2047
__global__ __launch_bounds__(512) void k_scanconv(const int* counts, int* rowptr, int* cursor, int n,
                                                  const void* xin, u16* xout) {
  if (blockIdx.x == 0) {
    __shared__ int lds[512];
    const int PER = 20;
    int t = threadIdx.x;
    int base = t * PER;
    int v[PER];
    int sum = 0;
#pragma unroll
    for (int i = 0; i < PER; i++) {
      int idx = base + i;
      v[i] = (idx < n) ? counts[idx] : 0;
      sum += v[i];
    }
    lds[t] = sum;
    __syncthreads();
    for (int off = 1; off < 512; off <<= 1) {
      int x = (t >= off) ? lds[t - off] : 0;
      __syncthreads();
      lds[t] += x;
      __syncthreads();
    }
    int run = (t > 0) ? lds[t - 1] : 0;
#pragma unroll
    for (int i = 0; i < PER; i++) {
      int idx = base + i;
      if (idx < n) {
        cursor[idx] = run;
        run += v[i];
        rowptr[idx + 1] = run;
      }
    }
    if (t == 0) rowptr[0] = 0;
    return;
  }
  int f = float_flag((const u16*)xin);
  const int total = NN * DIN_ / 8;
  for (int g = (blockIdx.x - 1) * 512 + threadIdx.x; g < total; g += CONVB * 512) {
    u16 o[8];
    if (f) {
      const float* p = (const float*)xin + (size_t)g * 8;
#pragma unroll
      for (int i = 0; i < 8; i++) o[i] = f2b(p[i]);
    } else {
      *(uint4*)o = *((const uint4*)xin + g);
    }
    *((uint4*)xout + g) = *(const uint4*)o;
  }
}

// ---------------- 64x128 MFMA GEMM body, BK=64 single-buffer (R3 known-good) ----------------
static __device__ __forceinline__ void gemm64_body(int id,
    const u16* __restrict__ A, int lda, const u16* __restrict__ Bt,
    const u16* __restrict__ bias, u16* __restrict__ C,
    int M, int N, int K, int act, int tiles_m, int ln_tiles_n) {
  __shared__ u16 sA[2 * 64 * 32];    // 8 KB
  __shared__ u16 sB[2 * 128 * 32];   // 16 KB
  int xcd = id & 7;
  int rest = id >> 3;
  int xt = rest & ((1 << ln_tiles_n) - 1);
  int yt = ((rest >> ln_tiles_n) << 3) + xcd;
  if (yt >= tiles_m) return;
  int m0 = yt << 6, n0 = xt << 7;
  int t = threadIdx.x;
  int wave = t >> 6, lane = t & 63;

  int srow = t >> 2;
  int sk = ((t & 3) ^ ((t >> 3) & 3)) * 8;  // XOR-swizzled k-chunk
  const u16* agp[2];
  u16* la[2];
#pragma unroll
  for (int h = 0; h < 2; h++) {
    int ra = m0 + srow;
    ra = ra < M ? ra : M - 1;
    agp[h] = A + (size_t)ra * lda + h * 32 + sk;
    la[h] = sA + h * 2048 + t * 8;
  }
  const u16* bgp[4];
  u16* lb[4];
#pragma unroll
  for (int q = 0; q < 4; q++) {
    int h = q >> 1;
    int row = ((q & 1) << 6) + srow;
    bgp[q] = Bt + (size_t)(n0 + row) * K + h * 32 + sk;
    lb[q] = sB + h * 4096 + (((q & 1) << 8) + t) * 8;
  }

  int wn = wave << 5;
  int lr = lane & 15;
  int kcs = (((lane >> 4) ^ ((lr >> 1) & 3))) * 8;

  f32x4 acc[4][2];
#pragma unroll
  for (int i = 0; i < 4; i++)
#pragma unroll
    for (int j = 0; j < 2; j++) acc[i][j] = (f32x4){0.f, 0.f, 0.f, 0.f};

  for (int k0 = 0; k0 < K; k0 += 64) {
#pragma unroll
    for (int h = 0; h < 2; h++) ASYNC_CP16(agp[h] + k0, la[h]);
#pragma unroll
    for (int q = 0; q < 4; q++) ASYNC_CP16(bgp[q] + k0, lb[q]);
    __syncthreads();
    bf16x8 a[2][4], b[2][2];
#pragma unroll
    for (int s = 0; s < 2; s++) {
#pragma unroll
      for (int i = 0; i < 4; i++) a[s][i] = *(const bf16x8*)(sA + s * 2048 + (i * 16 + lr) * 32 + kcs);
#pragma unroll
      for (int j = 0; j < 2; j++) b[s][j] = *(const bf16x8*)(sB + s * 4096 + (wn + j * 16 + lr) * 32 + kcs);
    }
#pragma unroll
    for (int s = 0; s < 2; s++)
#pragma unroll
      for (int i = 0; i < 4; i++)
#pragma unroll
        for (int j = 0; j < 2; j++)
          acc[i][j] = __builtin_amdgcn_mfma_f32_16x16x32_bf16(a[s][i], b[s][j], acc[i][j], 0, 0, 0);
    __syncthreads();
  }

  int rbase = (lane >> 4) << 2;
#pragma unroll
  for (int j = 0; j < 2; j++) {
    int colc = n0 + wn + j * 16 + lr;
    float bv = b2f(bias[colc]);
#pragma unroll
    for (int i = 0; i < 4; i++) {
#pragma unroll
      for (int r = 0; r < 4; r++) {
        int row = m0 + i * 16 + rbase + r;
        if (row < M) {
          float v = acc[i][j][r] + bv;
          if (act) v = fmaxf(v, 0.f);
          C[(size_t)row * N + colc] = f2b(v);
        }
      }
    }
  }
}

__global__ __launch_bounds__(256) void k_gemm64(const u16* __restrict__ A, int lda,
                                                const u16* __restrict__ Bt,
                                                const u16* __restrict__ bias,
                                                u16* __restrict__ C,
                                                int M, int N, int K, int act,
                                                int tiles_m, int ln_tiles_n) {
  gemm64_body(blockIdx.x, A, lda, Bt, bias, C, M, N, K, act, tiles_m, ln_tiles_n);
}

// ---------------- L4: scatter (needs cursor) + GEMM-1 (needs xc/comb0) — independent roles ----------------
struct SG {
  const int* esrc;
  const int* edst;
  int* cursor;
  int* col;
  const u16* A;    // xc
  const u16* Bt;   // comb0
  const u16* bias; // cb layer 0
  u16* C;          // X0
};
__global__ __launch_bounds__(256) void k_sg(SG a) {
  int b = blockIdx.x;
  if (b < SBLK) {
    int i = b * 256 + threadIdx.x;
    if (i < NE) {
      int p = atomicAdd(&a.cursor[a.edst[i]], 1);
      a.col[p] = a.esrc[i];
    } else if (i < NE + NN) {
      int v = i - NE;
      int p = atomicAdd(&a.cursor[v], 1);
      a.col[p] = v;  // self-loop
    }
    return;
  }
  gemm64_body(b - SBLK, a.A, 1024, a.Bt, a.bias, a.C, NN, 1024, 1024, 0, 157, 3);
}

// ---------------- single-pass GATv2 attention, 2-edge ILP, 1 exp per edge ----------------
__global__ __launch_bounds__(256) void k_attn5(u16* __restrict__ xlr,
                                               const u16* __restrict__ att, const u16* __restrict__ bias,
                                               const int* __restrict__ rowptr, const int* __restrict__ col,
                                               int n) {
  int node = (blockIdx.x * 256 + threadIdx.x) >> 6;
  if (node >= n) return;
  int lane = threadIdx.x & 63;
  int h0 = lane * 8;
  float a[8], r[8];
  load8(att + h0, a);
  load8(xlr + (size_t)node * 1024 + 512 + h0, r);
  int e0 = rowptr[node], e1 = rowptr[node + 1];

  float m = -3e38f, s = 0.f;
  float acc[8] = {0.f, 0.f, 0.f, 0.f, 0.f, 0.f, 0.f, 0.f};
  int j0 = col[e0];
  int j1 = col[(e0 + 1 < e1) ? e0 + 1 : e0];
  uint4 raw0 = *(const uint4*)(xlr + (size_t)j0 * 1024 + h0);
  uint4 raw1 = *(const uint4*)(xlr + (size_t)j1 * 1024 + h0);

  for (int e = e0; e < e1; e += 2) {
    bool has2 = (e + 1 < e1);
    int jn0 = col[(e + 2 < e1) ? e + 2 : e1 - 1];
    int jn1 = col[(e + 3 < e1) ? e + 3 : e1 - 1];
    uint4 p0 = *(const uint4*)(xlr + (size_t)jn0 * 1024 + h0);  // prefetch next pair
    uint4 p1 = *(const uint4*)(xlr + (size_t)jn1 * 1024 + h0);
    float x0[8], x1[8];
    unpack8(raw0, x0);
    unpack8(raw1, x1);
    float pa = 0.f, pb = 0.f;
#pragma unroll
    for (int i = 0; i < 8; i++) {
      float z0 = x0[i] + r[i];
      z0 = z0 > 0.f ? z0 : 0.2f * z0;
      pa = fmaf(a[i], z0, pa);
      float z1 = x1[i] + r[i];
      z1 = z1 > 0.f ? z1 : 0.2f * z1;
      pb = fmaf(a[i], z1, pb);
    }
#pragma unroll
    for (int off = 32; off >= 1; off >>= 1) {
      pa += __shfl_xor(pa, off);
      pb += __shfl_xor(pb, off);
    }
    // edge A: exactly one exp on the critical path (new-max edge has weight 1)
    if (pa > m) {
      float al = __expf(m - pa);  // first edge: exp(-inf)=0
      s = fmaf(s, al, 1.f);
#pragma unroll
      for (int i = 0; i < 8; i++) acc[i] = fmaf(acc[i], al, x0[i]);
      m = pa;
    } else {
      float w = __expf(pa - m);
      s += w;
#pragma unroll
      for (int i = 0; i < 8; i++) acc[i] = fmaf(w, x0[i], acc[i]);
    }
    if (has2) {
      if (pb > m) {
        float al = __expf(m - pb);
        s = fmaf(s, al, 1.f);
#pragma unroll
        for (int i = 0; i < 8; i++) acc[i] = fmaf(acc[i], al, x1[i]);
        m = pb;
      } else {
        float w = __expf(pb - m);
        s += w;
#pragma unroll
        for (int i = 0; i < 8; i++) acc[i] = fmaf(w, x1[i], acc[i]);
      }
    }
    raw0 = p0;
    raw1 = p1;
  }
  float inv = 1.f / (s + 1e-16f);

  float bv[8];
  load8(bias + h0, bv);
  uint4 o;
  u32 p8[8];
#pragma unroll
  for (int i = 0; i < 8; i++) {
    float v = fmaf(acc[i], inv, bv[i]);
    v = fmaxf(v, 0.f);
    p8[i] = f2b(v);
  }
  o.x = p8[0] | (p8[1] << 16);
  o.y = p8[2] | (p8[3] << 16);
  o.z = p8[4] | (p8[5] << 16);
  o.w = p8[6] | (p8[7] << 16);
  *(uint4*)(xlr + (size_t)node * 1024 + 512 + h0) = o;  // in-place over xr half
}

// ---------------- final linear (256->2) + softmax; fp32 out ----------------
__global__ __launch_bounds__(256) void k_head(const u16* __restrict__ h2, const u16* __restrict__ lw3,
                                              const u16* __restrict__ lb3, float* __restrict__ out, int n) {
  int row = (blockIdx.x * 256 + threadIdx.x) >> 6;
  if (row >= n) return;
  int lane = threadIdx.x & 63;
  int k0 = lane * 4;
  uint2 hu = *(const uint2*)(h2 + (size_t)row * 256 + k0);
  float hx[4];
  hx[0] = __builtin_bit_cast(float, hu.x << 16);
  hx[1] = __builtin_bit_cast(float, hu.x & 0xffff0000u);
  hx[2] = __builtin_bit_cast(float, hu.y << 16);
  hx[3] = __builtin_bit_cast(float, hu.y & 0xffff0000u);
  float wv[8];
  load8(lw3 + (size_t)k0 * 2, wv);
  float p0 = 0.f, p1 = 0.f;
#pragma unroll
  for (int i = 0; i < 4; i++) {
    p0 = fmaf(hx[i], wv[2 * i], p0);
    p1 = fmaf(hx[i], wv[2 * i + 1], p1);
  }
#pragma unroll
  for (int off = 32; off >= 1; off >>= 1) {
    p0 += __shfl_xor(p0, off);
    p1 += __shfl_xor(p1, off);
  }
  if (lane == 0) {
    float l0 = p0 + b2f(lb3[0]);
    float l1 = p1 + b2f(lb3[1]);
    float mx = fmaxf(l0, l1);
    float q0 = __expf(l0 - mx), q1 = __expf(l1 - mx);
    float si = 1.f / (q0 + q1);
    out[row * 2 + 0] = l0;
    out[row * 2 + 1] = l1;
    out[2 * n + row * 2 + 0] = q0 * si;
    out[2 * n + row * 2 + 1] = q1 * si;
  }
}

extern "C" void kernel_launch(void* const* d_in, const int* in_sizes, int n_in,
                              void* d_out, int out_size, void* d_ws, size_t ws_size,
                              hipStream_t stream) {
  (void)in_sizes; (void)n_in; (void)out_size; (void)ws_size;
  const void* x_raw = d_in[0];
  const void* ei_raw = d_in[1];
  const void *wl[4], *bl[4], *wr[4], *br[4], *att[4], *bg[4];
  for (int i = 0; i < 4; i++) {
    wl[i] = d_in[2 + i * 6 + 0];
    bl[i] = d_in[2 + i * 6 + 1];
    wr[i] = d_in[2 + i * 6 + 2];
    br[i] = d_in[2 + i * 6 + 3];
    att[i] = d_in[2 + i * 6 + 4];
    bg[i] = d_in[2 + i * 6 + 5];
  }
  const void* lw1 = d_in[26];
  const void* lb1 = d_in[27];
  const void* lw2 = d_in[28];
  const void* lb2 = d_in[29];
  const void* lw3 = d_in[30];
  const void* lb3 = d_in[31];

  size_t off = 0;
  auto alloc = [&](size_t bytes) -> void* {
    off = (off + 255) & ~(size_t)255;
    void* p = (char*)d_ws + off;
    off += bytes;
    return p;
  };
  int* esrc = (int*)alloc(NE * 4);
  int* edst = (int*)alloc(NE * 4);
  int* counts = (int*)alloc(NN * 4);
  int* rowptr = (int*)alloc((NN + 1) * 4);
  int* cursor = (int*)alloc(NN * 4);
  int* col = (int*)alloc((NE + NN) * 4);
  u16* cb = (u16*)alloc(4 * 1024 * 2);
  u16* attv = (u16*)alloc(4 * 512 * 2);
  u16* bgv = (u16*)alloc(4 * 512 * 2);
  u16* lb1v = (u16*)alloc(512 * 2);
  u16* lb2v = (u16*)alloc(256 * 2);
  u16* lw3v = (u16*)alloc(512 * 2);
  u16* lb3v = (u16*)alloc(2 * 2);
  u16* comb0 = (u16*)alloc((size_t)1024 * 1024 * 2);
  u16* combL[4];
  combL[0] = comb0;
  for (int l = 1; l < 4; l++) combL[l] = (u16*)alloc((size_t)1024 * 512 * 2);
  u16* lw1T = (u16*)alloc((size_t)512 * 512 * 2);
  u16* lw2T = (u16*)alloc((size_t)256 * 512 * 2);
  u16* xc = (u16*)alloc((size_t)NN * DIN_ * 2);
  u16* X0 = (u16*)alloc((size_t)NN * 1024 * 2);
  u16* X1 = (u16*)alloc((size_t)NN * 1024 * 2);
  u16* mlp1 = xc;                       // xc dead after layer-1 GEMM
  u16* mlp2 = xc + (size_t)NN * 512;

  // --- L0: zero degree counts ---
  hipMemsetAsync(counts, 0, NN * 4, stream);

  // --- L1: edges + vec converts + weight transposes (all input-only work) ---
  Prep pa;
  pa.ei = ei_raw;
  pa.esrc = esrc;
  pa.edst = edst;
  pa.counts = counts;
  pa.xin = x_raw;
  for (int l = 0; l < 4; l++) {
    pa.vin[l * 4 + 0] = bl[l];  pa.vout[l * 4 + 0] = cb + l * 1024;        pa.vn[l * 4 + 0] = 512;
    pa.vin[l * 4 + 1] = br[l];  pa.vout[l * 4 + 1] = cb + l * 1024 + 512;  pa.vn[l * 4 + 1] = 512;
    pa.vin[l * 4 + 2] = att[l]; pa.vout[l * 4 + 2] = attv + l * 512;       pa.vn[l * 4 + 2] = 512;
    pa.vin[l * 4 + 3] = bg[l];  pa.vout[l * 4 + 3] = bgv + l * 512;        pa.vn[l * 4 + 3] = 512;
  }
  pa.vin[16] = lb1; pa.vout[16] = lb1v; pa.vn[16] = 512;
  pa.vin[17] = lb2; pa.vout[17] = lb2v; pa.vn[17] = 256;
  pa.vin[18] = lw3; pa.vout[18] = lw3v; pa.vn[18] = 512;
  pa.vin[19] = lb3; pa.vout[19] = lb3v; pa.vn[19] = 2;
  const void* tin[10] = {wl[0], wr[0], wl[1], wr[1], wl[2], wr[2], wl[3], wr[3], lw1, lw2};
  u16* tout[10] = {comb0, comb0 + (size_t)512 * 1024,
                   combL[1], combL[1] + (size_t)512 * 512,
                   combL[2], combL[2] + (size_t)512 * 512,
                   combL[3], combL[3] + (size_t)512 * 512,
                   lw1T, lw2T};
  int tK[10] = {1024, 1024, 512, 512, 512, 512, 512, 512, 512, 512};
  int tN[10] = {512, 512, 512, 512, 512, 512, 512, 512, 512, 256};
  int acc_off = 0;
  for (int i = 0; i < 10; i++) {
    pa.tin[i] = tin[i];
    pa.tout[i] = tout[i];
    pa.tK[i] = tK[i];
    pa.tN[i] = tN[i];
    pa.toff[i] = acc_off;
    acc_off += (tN[i] >> 5) * (tK[i] >> 5);
  }
  k_prep<<<SBLK + 20 + acc_off, 256, 0, stream>>>(pa);

  // --- L2: scan (block 0) + xc conversion ---
  k_scanconv<<<1 + CONVB, 512, 0, stream>>>(counts, rowptr, cursor, NN, x_raw, xc);

  // --- L3: scatter + GEMM-1 (independent roles, one launch) ---
  SG sg;
  sg.esrc = esrc;
  sg.edst = edst;
  sg.cursor = cursor;
  sg.col = col;
  sg.A = xc;
  sg.Bt = comb0;
  sg.bias = cb + 0 * 1024;
  sg.C = X0;
  k_sg<<<SBLK + 1280, 256, 0, stream>>>(sg);

  auto gemm = [&](const u16* A, int lda, const u16* Bt, const u16* bias, u16* C,
                  int M, int Nn, int K, int act) {
    int tiles_m = (M + 63) >> 6;
    int tiles_n = Nn >> 7;
    int ln = (tiles_n == 8) ? 3 : (tiles_n == 4) ? 2 : 1;
    int mgrp = (tiles_m + 7) >> 3;
    int blocks = (mgrp << 3) * tiles_n;
    k_gemm64<<<blocks, 256, 0, stream>>>(A, lda, Bt, bias, C, M, Nn, K, act, tiles_m, ln);
  };
  auto attn = [&](u16* xlr, int l) {
    k_attn5<<<(NN * 64 + 255) / 256, 256, 0, stream>>>(xlr, attv + l * 512, bgv + l * 512,
                                                       rowptr, col, NN);
  };

  // Layer 1 attn
  attn(X0, 0);
  // Layer 2
  gemm(X0 + 512, 1024, combL[1], cb + 1 * 1024, X1, NN, 1024, 512, 0);
  attn(X1, 1);
  // Layer 3
  gemm(X1 + 512, 1024, combL[2], cb + 2 * 1024, X0, NN, 1024, 512, 0);
  attn(X0, 2);
  // Layer 4
  gemm(X0 + 512, 1024, combL[3], cb + 3 * 1024, X1, NN, 1024, 512, 0);
  attn(X1, 3);

  // MLP head (split: known-good occupancy)
  gemm(X1 + 512, 1024, lw1T, lb1v, mlp1, NN, 512, 512, 1);
  gemm(mlp1, 512, lw2T, lb2v, mlp2, NN, 256, 512, 1);
  k_head<<<(NN * 64 + 255) / 256, 256, 0, stream>>>(mlp2, lw3v, lb3v, (float*)d_out, NN);
}